// Round 1
// baseline (776.493 us; speedup 1.0000x reference)
//
#include <hip/hip_runtime.h>

#define MTOK   4096   // B*T
#define DD     1024
#define HH     4096
#define EE     8
#define NPAIRS 8192   // MTOK * TOP_K
#define PADM   128    // tile-overrun pad rows

typedef __attribute__((ext_vector_type(8))) _Float16 half8;
typedef __attribute__((ext_vector_type(4))) _Float16 half4;
typedef __attribute__((ext_vector_type(4))) float    f32x4;

__device__ __forceinline__ void gload_lds16(const void* g, void* l) {
  __builtin_amdgcn_global_load_lds((const __attribute__((address_space(1))) void*)g,
                                   (__attribute__((address_space(3))) void*)l,
                                   16, 0, 0);
}

__global__ void k_init(int* counts) {
  if (threadIdx.x < EE) counts[threadIdx.x] = 0;
}

// one wave per token: logits = x[t] @ gate_w + gate_b; softmax; top-2
__global__ __launch_bounds__(256) void k_gate(
    const float* __restrict__ x, const float* __restrict__ gw,
    const float* __restrict__ gb, int* __restrict__ counts,
    int* __restrict__ topi, float* __restrict__ topg)
{
  __shared__ float W[EE][DD];  // gate_w transposed [e][k], 32 KB
  int tid = threadIdx.x;
  for (int i = tid; i < DD*EE/4; i += 256) {
    f32x4 v = ((const f32x4*)gw)[i];
    int flat = i*4;                 // flat = k*8 + e
#pragma unroll
    for (int j = 0; j < 4; ++j) { int f = flat + j; W[f & 7][f >> 3] = v[j]; }
  }
  __syncthreads();
  int w = tid >> 6, lane = tid & 63;
  int t = blockIdx.x*4 + w;
  float acc[EE];
#pragma unroll
  for (int e = 0; e < EE; ++e) acc[e] = 0.f;
  const float* xr = x + (size_t)t*DD;
  for (int kk = 0; kk < DD/64; ++kk) {
    int k = kk*64 + lane;
    float xv = xr[k];
#pragma unroll
    for (int e = 0; e < EE; ++e) acc[e] += xv * W[e][k];
  }
#pragma unroll
  for (int off = 32; off >= 1; off >>= 1) {
#pragma unroll
    for (int e = 0; e < EE; ++e) acc[e] += __shfl_down(acc[e], off, 64);
  }
  if (lane == 0) {
#pragma unroll
    for (int e = 0; e < EE; ++e) acc[e] += gb[e];
    int i0 = 0;
#pragma unroll
    for (int e = 1; e < EE; ++e) if (acc[e] > acc[i0]) i0 = e;
    int i1 = (i0 == 0) ? 1 : 0;
#pragma unroll
    for (int e = 0; e < EE; ++e)
      if (e != i0 && e != i1 && acc[e] > acc[i1]) i1 = e;
    float m = acc[i0], s = 0.f, ex[EE];
#pragma unroll
    for (int e = 0; e < EE; ++e) { ex[e] = expf(acc[e] - m); s += ex[e]; }
    float inv = 1.f / s;
    topi[2*t] = i0;  topi[2*t+1] = i1;
    topg[2*t] = ex[i0]*inv;  topg[2*t+1] = ex[i1]*inv;
    atomicAdd(&counts[i0], 1);
    atomicAdd(&counts[i1], 1);
  }
}

__global__ void k_prefix(const int* counts, int* offs, int* cursor) {
  if (threadIdx.x == 0) {
    int s = 0;
    for (int e = 0; e < EE; ++e) { offs[e] = s; cursor[e] = s; s += counts[e]; }
    offs[EE] = s;
  }
}

__global__ void k_build(const int* __restrict__ topi, const float* __restrict__ topg,
                        int* __restrict__ cursor, int* __restrict__ tok_of,
                        float* __restrict__ gate_of, int* __restrict__ slot_of)
{
  int t = blockIdx.x*blockDim.x + threadIdx.x;
  if (t >= MTOK) return;
#pragma unroll
  for (int k = 0; k < 2; ++k) {
    int e = topi[2*t+k];
    int pos = atomicAdd(&cursor[e], 1);
    tok_of[pos]  = t;
    gate_of[pos] = topg[2*t+k];
    slot_of[2*t+k] = pos;
  }
}

// pack gathered token rows into contiguous fp16 A matrix
__global__ __launch_bounds__(256) void k_gather(
    const float* __restrict__ x, const int* __restrict__ tok_of,
    _Float16* __restrict__ xg)
{
  int p = blockIdx.x;
  int t = tok_of[p];
  const f32x4* src = (const f32x4*)(x + (size_t)t*DD);
  half4* dst = (half4*)(xg + (size_t)p*DD);
  int i = threadIdx.x;           // DD/4 == 256 == blockDim
  f32x4 v = src[i];
  half4 h = { (_Float16)v[0], (_Float16)v[1], (_Float16)v[2], (_Float16)v[3] };
  dst[i] = h;
}

// in: [E][Kd][Nd] f32  ->  out: [E][Nd][Kd] f16   (B^T for the GEMMs)
__global__ __launch_bounds__(256) void k_transpose(
    const float* __restrict__ in, _Float16* __restrict__ out, int Kd, int Nd)
{
  __shared__ _Float16 tile[64][72];   // +8 halves pad
  int e = blockIdx.z;
  int n0 = blockIdx.x*64, k0 = blockIdx.y*64;
  int tid = threadIdx.x;
  int rq = tid >> 4, c4 = (tid & 15)*4;
  const float* src = in + (size_t)e*Kd*Nd;
#pragma unroll
  for (int rr = 0; rr < 4; ++rr) {
    int kr = rr*16 + rq;
    f32x4 v = *(const f32x4*)(src + (size_t)(k0+kr)*Nd + n0 + c4);
#pragma unroll
    for (int j = 0; j < 4; ++j) tile[c4+j][kr] = (_Float16)v[j];
  }
  __syncthreads();
  _Float16* dst = out + (size_t)e*Nd*Kd;
#pragma unroll
  for (int rr = 0; rr < 4; ++rr) {
    int nr = rr*16 + rq;
    half4 h;
#pragma unroll
    for (int j = 0; j < 4; ++j) h[j] = tile[nr][c4+j];
    *(half4*)(dst + (size_t)(n0+nr)*Kd + k0 + c4) = h;
  }
}

// grouped GEMM over experts. A packed [rows][Kdim] f16, Bt [E][Ndim][Kdim] f16.
// EPI=0: Ch = relu(A@B + b1) as f16.   EPI=1: Cf = (A@B + b2) * gate as f32.
template<int EPI>
__global__ __launch_bounds__(256) void k_gemm(
    const _Float16* __restrict__ A, const _Float16* __restrict__ Bt,
    const float* __restrict__ bias, const int* __restrict__ offs,
    const int* __restrict__ counts, const float* __restrict__ gate_of,
    _Float16* __restrict__ Ch, float* __restrict__ Cf, int Kdim, int Ndim)
{
  int e = blockIdx.z;
  int cnt = counts[e];
  int m0 = blockIdx.y*128;
  if (m0 >= cnt) return;           // uniform early-exit
  int n0 = blockIdx.x*128;
  int row_base = offs[e] + m0;

  __shared__ alignas(16) _Float16 lsA[128*64];
  __shared__ alignas(16) _Float16 lsB[128*64];

  int tid = threadIdx.x, w = tid >> 6, lane = tid & 63;
  int wr = w >> 1, wc = w & 1;

  f32x4 acc[4][4];
#pragma unroll
  for (int ni = 0; ni < 4; ++ni) {
    float bv = bias[(size_t)e*Ndim + n0 + wc*64 + ni*16 + (lane & 15)];
#pragma unroll
    for (int mi = 0; mi < 4; ++mi) acc[mi][ni] = (f32x4){bv, bv, bv, bv};
  }

  // staging map: linear LDS dest (wave-uniform base + lane*16), global source
  // pre-swizzled by the same XOR the reads use (both-sides rule).
  int arow[4], acol[4];
#pragma unroll
  for (int i = 0; i < 4; ++i) {
    int o = w*4096 + i*1024 + lane*16;   // byte offset in 16 KB tile
    int row = o >> 7;                    // 128 B per row (64 halves)
    int chunk = (o >> 4) & 7;
    arow[i] = row;
    acol[i] = (chunk ^ (row & 7)) * 8;   // halves
  }

  const _Float16* Arow = A + (size_t)row_base*Kdim;
  const _Float16* Brow = Bt + ((size_t)e*Ndim + n0)*Kdim;

  for (int k0 = 0; k0 < Kdim; k0 += 64) {
#pragma unroll
    for (int i = 0; i < 4; ++i)
      gload_lds16(Arow + (size_t)arow[i]*Kdim + k0 + acol[i],
                  (char*)lsA + w*4096 + i*1024);
#pragma unroll
    for (int i = 0; i < 4; ++i)
      gload_lds16(Brow + (size_t)arow[i]*Kdim + k0 + acol[i],
                  (char*)lsB + w*4096 + i*1024);
    __syncthreads();   // drains vmcnt before barrier
#pragma unroll
    for (int ks = 0; ks < 2; ++ks) {
      half8 af[4], bf[4];
#pragma unroll
      for (int mi = 0; mi < 4; ++mi) {
        int r = wr*64 + mi*16 + (lane & 15);
        int byt = (r*128 + ks*64 + ((lane >> 4) << 4)) ^ ((r & 7) << 4);
        af[mi] = *(const half8*)((const char*)lsA + byt);
      }
#pragma unroll
      for (int ni = 0; ni < 4; ++ni) {
        int r = wc*64 + ni*16 + (lane & 15);
        int byt = (r*128 + ks*64 + ((lane >> 4) << 4)) ^ ((r & 7) << 4);
        bf[ni] = *(const half8*)((const char*)lsB + byt);
      }
#pragma unroll
      for (int mi = 0; mi < 4; ++mi)
#pragma unroll
        for (int ni = 0; ni < 4; ++ni)
          acc[mi][ni] = __builtin_amdgcn_mfma_f32_16x16x32_f16(af[mi], bf[ni], acc[mi][ni], 0, 0, 0);
    }
    __syncthreads();
  }

  // C layout: col = lane&15, row = (lane>>4)*4 + reg  [m89/m91 verified]
#pragma unroll
  for (int mi = 0; mi < 4; ++mi) {
    int rl = wr*64 + mi*16 + ((lane >> 4) << 2);
#pragma unroll
    for (int ni = 0; ni < 4; ++ni) {
      int cl = n0 + wc*64 + ni*16 + (lane & 15);
#pragma unroll
      for (int r = 0; r < 4; ++r) {
        if (m0 + rl + r >= cnt) continue;
        size_t grow = (size_t)(row_base + rl + r);
        float v = acc[mi][ni][r];
        if (EPI == 0) Ch[grow*Ndim + cl] = (_Float16)fmaxf(v, 0.f);
        else          Cf[grow*Ndim + cl] = v * gate_of[grow];
      }
    }
  }
}

__global__ __launch_bounds__(256) void k_combine(
    const float* __restrict__ o2, const int* __restrict__ slot_of,
    float* __restrict__ out)
{
  int t = blockIdx.x;
  int s0 = slot_of[2*t], s1 = slot_of[2*t+1];
  const f32x4* a = (const f32x4*)(o2 + (size_t)s0*DD);
  const f32x4* b = (const f32x4*)(o2 + (size_t)s1*DD);
  f32x4* o = (f32x4*)(out + (size_t)t*DD);
  int i = threadIdx.x;   // DD/4 == 256
  o[i] = a[i] + b[i];
}

extern "C" void kernel_launch(void* const* d_in, const int* in_sizes, int n_in,
                              void* d_out, int out_size, void* d_ws, size_t ws_size,
                              hipStream_t stream)
{
  const float* x  = (const float*)d_in[0];
  const float* gw = (const float*)d_in[1];
  const float* gb = (const float*)d_in[2];
  const float* w1 = (const float*)d_in[3];
  const float* b1 = (const float*)d_in[4];
  const float* w2 = (const float*)d_in[5];
  const float* b2 = (const float*)d_in[6];
  float* out = (float*)d_out;
  char* ws = (char*)d_ws;

  size_t off = 0;
  auto alloc = [&](size_t b) {
    off = (off + 255) & ~(size_t)255;
    size_t o = off; off += b; return o;
  };
  int*   counts  = (int*)  (ws + alloc(EE*4));
  int*   offs    = (int*)  (ws + alloc((EE+1)*4));
  int*   cursor  = (int*)  (ws + alloc(EE*4));
  int*   topi    = (int*)  (ws + alloc((size_t)MTOK*2*4));
  float* topg    = (float*)(ws + alloc((size_t)MTOK*2*4));
  int*   tok_of  = (int*)  (ws + alloc((size_t)NPAIRS*4));
  float* gate_of = (float*)(ws + alloc((size_t)NPAIRS*4));
  int*   slot_of = (int*)  (ws + alloc((size_t)MTOK*2*4));
  _Float16* xg  = (_Float16*)(ws + alloc((size_t)(NPAIRS+PADM)*DD*2));
  _Float16* hb  = (_Float16*)(ws + alloc((size_t)(NPAIRS+PADM)*HH*2));
  _Float16* w1t = (_Float16*)(ws + alloc((size_t)EE*HH*DD*2));
  _Float16* w2t = (_Float16*)(ws + alloc((size_t)EE*DD*HH*2));
  float* o2 = (float*)w1t;   // alias: w1t is dead after gemm1; o2 (33.5 MB) fits

  k_init<<<1, 64, 0, stream>>>(counts);
  k_gate<<<MTOK/4, 256, 0, stream>>>(x, gw, gb, counts, topi, topg);
  k_prefix<<<1, 64, 0, stream>>>(counts, offs, cursor);
  k_build<<<MTOK/256, 256, 0, stream>>>(topi, topg, cursor, tok_of, gate_of, slot_of);
  k_gather<<<NPAIRS, 256, 0, stream>>>(x, tok_of, xg);
  k_transpose<<<dim3(HH/64, DD/64, EE), 256, 0, stream>>>(w1, w1t, DD, HH);
  k_transpose<<<dim3(DD/64, HH/64, EE), 256, 0, stream>>>(w2, w2t, HH, DD);
  k_gemm<0><<<dim3(HH/128, MTOK/128, EE), 256, 0, stream>>>(
      xg, w1t, b1, offs, counts, nullptr, hb, nullptr, DD, HH);
  k_gemm<1><<<dim3(DD/128, MTOK/128, EE), 256, 0, stream>>>(
      hb, w2t, b2, offs, counts, gate_of, nullptr, o2, HH, DD);
  k_combine<<<MTOK, 256, 0, stream>>>(o2, slot_of, out);
}

// Round 2
// 678.970 us; speedup vs baseline: 1.1436x; 1.1436x over previous
//
#include <hip/hip_runtime.h>

#define MTOK   4096   // B*T
#define DD     1024
#define HH     4096
#define EE     8
#define NPAIRS 8192   // MTOK * TOP_K
#define PADM   128    // tile-overrun pad rows

typedef __attribute__((ext_vector_type(8))) _Float16 half8;
typedef __attribute__((ext_vector_type(4))) _Float16 half4;
typedef __attribute__((ext_vector_type(4))) float    f32x4;

__device__ __forceinline__ void gload_lds16(const void* g, void* l) {
  __builtin_amdgcn_global_load_lds((const __attribute__((address_space(1))) void*)g,
                                   (__attribute__((address_space(3))) void*)l,
                                   16, 0, 0);
}

__global__ void k_init(int* counts) {
  if (threadIdx.x < EE) counts[threadIdx.x] = 0;
}

// one wave per token: logits = x[t] @ gate_w + gate_b; softmax; top-2
__global__ __launch_bounds__(256) void k_gate(
    const float* __restrict__ x, const float* __restrict__ gw,
    const float* __restrict__ gb, int* __restrict__ counts,
    int* __restrict__ topi, float* __restrict__ topg)
{
  __shared__ float W[EE][DD];  // gate_w transposed [e][k], 32 KB
  int tid = threadIdx.x;
  for (int i = tid; i < DD*EE/4; i += 256) {
    f32x4 v = ((const f32x4*)gw)[i];
    int flat = i*4;                 // flat = k*8 + e
#pragma unroll
    for (int j = 0; j < 4; ++j) { int f = flat + j; W[f & 7][f >> 3] = v[j]; }
  }
  __syncthreads();
  int w = tid >> 6, lane = tid & 63;
  int t = blockIdx.x*4 + w;
  float acc[EE];
#pragma unroll
  for (int e = 0; e < EE; ++e) acc[e] = 0.f;
  const float* xr = x + (size_t)t*DD;
  for (int kk = 0; kk < DD/64; ++kk) {
    int k = kk*64 + lane;
    float xv = xr[k];
#pragma unroll
    for (int e = 0; e < EE; ++e) acc[e] += xv * W[e][k];
  }
#pragma unroll
  for (int off = 32; off >= 1; off >>= 1) {
#pragma unroll
    for (int e = 0; e < EE; ++e) acc[e] += __shfl_down(acc[e], off, 64);
  }
  if (lane == 0) {
#pragma unroll
    for (int e = 0; e < EE; ++e) acc[e] += gb[e];
    int i0 = 0;
#pragma unroll
    for (int e = 1; e < EE; ++e) if (acc[e] > acc[i0]) i0 = e;
    int i1 = (i0 == 0) ? 1 : 0;
#pragma unroll
    for (int e = 0; e < EE; ++e)
      if (e != i0 && e != i1 && acc[e] > acc[i1]) i1 = e;
    float m = acc[i0], s = 0.f, ex[EE];
#pragma unroll
    for (int e = 0; e < EE; ++e) { ex[e] = expf(acc[e] - m); s += ex[e]; }
    float inv = 1.f / s;
    topi[2*t] = i0;  topi[2*t+1] = i1;
    topg[2*t] = ex[i0]*inv;  topg[2*t+1] = ex[i1]*inv;
    atomicAdd(&counts[i0], 1);
    atomicAdd(&counts[i1], 1);
  }
}

__global__ void k_prefix(const int* counts, int* offs, int* cursor) {
  if (threadIdx.x == 0) {
    int s = 0;
    for (int e = 0; e < EE; ++e) { offs[e] = s; cursor[e] = s; s += counts[e]; }
    offs[EE] = s;
  }
}

__global__ void k_build(const int* __restrict__ topi, const float* __restrict__ topg,
                        int* __restrict__ cursor, int* __restrict__ tok_of,
                        float* __restrict__ gate_of, int* __restrict__ slot_of)
{
  int t = blockIdx.x*blockDim.x + threadIdx.x;
  if (t >= MTOK) return;
#pragma unroll
  for (int k = 0; k < 2; ++k) {
    int e = topi[2*t+k];
    int pos = atomicAdd(&cursor[e], 1);
    tok_of[pos]  = t;
    gate_of[pos] = topg[2*t+k];
    slot_of[2*t+k] = pos;
  }
}

// pack gathered token rows into contiguous fp16 A matrix
__global__ __launch_bounds__(256) void k_gather(
    const float* __restrict__ x, const int* __restrict__ tok_of,
    _Float16* __restrict__ xg)
{
  int p = blockIdx.x;
  int t = tok_of[p];
  const f32x4* src = (const f32x4*)(x + (size_t)t*DD);
  half4* dst = (half4*)(xg + (size_t)p*DD);
  int i = threadIdx.x;           // DD/4 == 256 == blockDim
  f32x4 v = src[i];
  half4 h = { (_Float16)v[0], (_Float16)v[1], (_Float16)v[2], (_Float16)v[3] };
  dst[i] = h;
}

// in: [E][Kd][Nd] f32  ->  out: [E][Nd][Kd] f16   (B^T for the GEMMs)
__global__ __launch_bounds__(256) void k_transpose(
    const float* __restrict__ in, _Float16* __restrict__ out, int Kd, int Nd)
{
  __shared__ _Float16 tile[64][72];   // +8 halves pad
  int e = blockIdx.z;
  int n0 = blockIdx.x*64, k0 = blockIdx.y*64;
  int tid = threadIdx.x;
  int rq = tid >> 4, c4 = (tid & 15)*4;
  const float* src = in + (size_t)e*Kd*Nd;
#pragma unroll
  for (int rr = 0; rr < 4; ++rr) {
    int kr = rr*16 + rq;
    f32x4 v = *(const f32x4*)(src + (size_t)(k0+kr)*Nd + n0 + c4);
#pragma unroll
    for (int j = 0; j < 4; ++j) tile[c4+j][kr] = (_Float16)v[j];
  }
  __syncthreads();
  _Float16* dst = out + (size_t)e*Nd*Kd;
#pragma unroll
  for (int rr = 0; rr < 4; ++rr) {
    int nr = rr*16 + rq;
    half4 h;
#pragma unroll
    for (int j = 0; j < 4; ++j) h[j] = tile[nr][c4+j];
    *(half4*)(dst + (size_t)(n0+nr)*Kd + k0 + c4) = h;
  }
}

// grouped GEMM over experts, 2-phase double-buffered pipeline.
// A packed [rows][KD] f16, Bt [E][ND][KD] f16.
// EPI=0: Ch = relu(A@B + b1) as f16.   EPI=1 (split-K KS): Cf slices,
//   slice ks: (A@B_kslice + (ks==0 ? b2 : 0)) * gate, fp32.
template<int EPI, int KS, int KD, int ND>
__global__ __launch_bounds__(256) void k_gemm(
    const _Float16* __restrict__ A, const _Float16* __restrict__ Bt,
    const float* __restrict__ bias, const int* __restrict__ offs,
    const int* __restrict__ counts, const float* __restrict__ gate_of,
    _Float16* __restrict__ Ch, float* __restrict__ Cf)
{
  constexpr int NT = ND >> 7;        // n-tiles
  constexpr int MT = MTOK >> 7;      // m-tiles (32)
  // XCD-bijective swizzle: chunk-major, n fastest within chunk (A-panel L2 reuse)
  int total = NT * MT * EE * KS;     // divisible by 8
  int lid = blockIdx.x;
  int logical = (lid & 7) * (total >> 3) + (lid >> 3);
  int n  = logical % NT;
  int rem = logical / NT;
  int m  = rem % MT;
  int z  = rem / MT;
  int e  = z / KS, ks = z % KS;

  int cnt = counts[e];
  int m0 = m << 7;
  if (m0 >= cnt) return;
  int n0 = n << 7;
  int row_base = offs[e] + m0;
  constexpr int Kper = KD / KS;
  int kbeg = ks * Kper;

  constexpr int LSZ = (EPI == 1) ? (128*132*4) : 65536;  // >= 64KB dbuf
  __shared__ alignas(16) char ls[LSZ];

  int tid = threadIdx.x, w = tid >> 6, lane = tid & 63;
  int wr = w >> 1, wc = w & 1;

  f32x4 acc[4][4];
#pragma unroll
  for (int ni = 0; ni < 4; ++ni) {
    float bv = (EPI == 0 || ks == 0)
             ? bias[(size_t)e*ND + n0 + wc*64 + ni*16 + (lane & 15)] : 0.f;
#pragma unroll
    for (int mi = 0; mi < 4; ++mi) acc[mi][ni] = (f32x4){bv, bv, bv, bv};
  }

  // staging map: linear LDS dest (wave-uniform base + lane*16), global source
  // pre-swizzled by the same XOR the reads use (both-sides rule).
  int arow[4], acol[4];
#pragma unroll
  for (int i = 0; i < 4; ++i) {
    int o = w*4096 + i*1024 + lane*16;   // byte offset in 16 KB tile
    int row = o >> 7;                    // 128 B per row (64 halves)
    int chunk = (o >> 4) & 7;
    arow[i] = row;
    acol[i] = (chunk ^ (row & 7)) * 8;   // halves
  }

  const _Float16* Arow = A + (size_t)row_base*KD + kbeg;
  const _Float16* Brow = Bt + ((size_t)e*ND + n0)*KD + kbeg;

  auto STAGE = [&](int buf, int k0) {
    char* dA = ls + buf*16384;
    char* dB = ls + 32768 + buf*16384;
#pragma unroll
    for (int i = 0; i < 4; ++i)
      gload_lds16(Arow + (size_t)arow[i]*KD + k0 + acol[i], dA + w*4096 + i*1024);
#pragma unroll
    for (int i = 0; i < 4; ++i)
      gload_lds16(Brow + (size_t)arow[i]*KD + k0 + acol[i], dB + w*4096 + i*1024);
  };

  auto COMPUTE = [&](int buf) {
    const char* sA = ls + buf*16384;
    const char* sB = ls + 32768 + buf*16384;
#pragma unroll
    for (int ks2 = 0; ks2 < 2; ++ks2) {
      half8 af[4], bf[4];
#pragma unroll
      for (int mi = 0; mi < 4; ++mi) {
        int r = wr*64 + mi*16 + (lane & 15);
        int byt = (r*128 + ks2*64 + ((lane >> 4) << 4)) ^ ((r & 7) << 4);
        af[mi] = *(const half8*)(sA + byt);
      }
#pragma unroll
      for (int ni = 0; ni < 4; ++ni) {
        int r = wc*64 + ni*16 + (lane & 15);
        int byt = (r*128 + ks2*64 + ((lane >> 4) << 4)) ^ ((r & 7) << 4);
        bf[ni] = *(const half8*)(sB + byt);
      }
#pragma unroll
      for (int mi = 0; mi < 4; ++mi)
#pragma unroll
        for (int ni = 0; ni < 4; ++ni)
          acc[mi][ni] = __builtin_amdgcn_mfma_f32_16x16x32_f16(af[mi], bf[ni], acc[mi][ni], 0, 0, 0);
    }
  };

  constexpr int NTILES = Kper >> 6;
  STAGE(0, 0);
  __syncthreads();                 // drains vmcnt: buf0 ready
  int cur = 0;
  for (int t = 0; t < NTILES; ++t) {
    if (t + 1 < NTILES) STAGE(cur ^ 1, (t + 1) << 6);  // overlap with compute
    COMPUTE(cur);
    __syncthreads();               // drains vmcnt+lgkmcnt: next buf ready, cur reusable
    cur ^= 1;
  }

  // ---- epilogue: fragment -> LDS repack -> coalesced vector stores ----
  // C frag layout: col = lane&15, row = (lane>>4)*4 + reg  [m89/m91 verified]
  if (EPI == 0) {
    _Float16* T = (_Float16*)ls;   // [128][136] halves, padded pitch
#pragma unroll
    for (int mi = 0; mi < 4; ++mi) {
      int rl = wr*64 + mi*16 + ((lane >> 4) << 2);
#pragma unroll
      for (int ni = 0; ni < 4; ++ni) {
        int cl = wc*64 + ni*16 + (lane & 15);
#pragma unroll
        for (int r = 0; r < 4; ++r)
          T[(rl + r)*136 + cl] = (_Float16)fmaxf(acc[mi][ni][r], 0.f);
      }
    }
    __syncthreads();
#pragma unroll
    for (int p = 0; p < 8; ++p) {
      int flat = p*2048 + tid*8;
      int row = flat >> 7, col = flat & 127;
      if (m0 + row < cnt) {
        half8 hv = *(const half8*)&T[row*136 + col];
        *(half8*)(Ch + (size_t)(row_base + row)*ND + n0 + col) = hv;
      }
    }
  } else {
    float* T = (float*)ls;         // [128][132] f32, padded pitch
#pragma unroll
    for (int mi = 0; mi < 4; ++mi) {
      int rl = wr*64 + mi*16 + ((lane >> 4) << 2);
#pragma unroll
      for (int ni = 0; ni < 4; ++ni) {
        int cl = wc*64 + ni*16 + (lane & 15);
#pragma unroll
        for (int r = 0; r < 4; ++r)
          T[(rl + r)*132 + cl] = acc[mi][ni][r];
      }
    }
    __syncthreads();
    float* Cs = Cf + (size_t)ks * NPAIRS * ND;
#pragma unroll
    for (int p = 0; p < 16; ++p) {
      int flat = p*1024 + tid*4;
      int row = flat >> 7, col = flat & 127;
      if (m0 + row < cnt) {
        size_t grow = (size_t)(row_base + row);
        f32x4 v = *(const f32x4*)&T[row*132 + col];
        float g = gate_of[grow];
        v[0] *= g; v[1] *= g; v[2] *= g; v[3] *= g;
        *(f32x4*)(Cs + grow*ND + n0 + col) = v;
      }
    }
  }
}

__global__ __launch_bounds__(256) void k_combine(
    const float* __restrict__ o2, const int* __restrict__ slot_of,
    float* __restrict__ out)
{
  int t = blockIdx.x;
  int s0 = slot_of[2*t], s1 = slot_of[2*t+1];
  const f32x4* a0 = (const f32x4*)(o2 + (size_t)s0*DD);
  const f32x4* a1 = (const f32x4*)(o2 + ((size_t)NPAIRS + s0)*DD);
  const f32x4* b0 = (const f32x4*)(o2 + (size_t)s1*DD);
  const f32x4* b1 = (const f32x4*)(o2 + ((size_t)NPAIRS + s1)*DD);
  f32x4* o = (f32x4*)(out + (size_t)t*DD);
  int i = threadIdx.x;   // DD/4 == 256
  o[i] = a0[i] + a1[i] + b0[i] + b1[i];
}

extern "C" void kernel_launch(void* const* d_in, const int* in_sizes, int n_in,
                              void* d_out, int out_size, void* d_ws, size_t ws_size,
                              hipStream_t stream)
{
  const float* x  = (const float*)d_in[0];
  const float* gw = (const float*)d_in[1];
  const float* gb = (const float*)d_in[2];
  const float* w1 = (const float*)d_in[3];
  const float* b1 = (const float*)d_in[4];
  const float* w2 = (const float*)d_in[5];
  const float* b2 = (const float*)d_in[6];
  float* out = (float*)d_out;
  char* ws = (char*)d_ws;

  size_t off = 0;
  auto alloc = [&](size_t b) {
    off = (off + 255) & ~(size_t)255;
    size_t o = off; off += b; return o;
  };
  int*   counts  = (int*)  (ws + alloc(EE*4));
  int*   offs    = (int*)  (ws + alloc((EE+1)*4));
  int*   cursor  = (int*)  (ws + alloc(EE*4));
  int*   topi    = (int*)  (ws + alloc((size_t)MTOK*2*4));
  float* topg    = (float*)(ws + alloc((size_t)MTOK*2*4));
  int*   tok_of  = (int*)  (ws + alloc((size_t)NPAIRS*4));
  float* gate_of = (float*)(ws + alloc((size_t)NPAIRS*4));
  int*   slot_of = (int*)  (ws + alloc((size_t)MTOK*2*4));
  _Float16* xg  = (_Float16*)(ws + alloc((size_t)(NPAIRS+PADM)*DD*2));
  _Float16* hb  = (_Float16*)(ws + alloc((size_t)(NPAIRS+PADM)*HH*2));
  _Float16* w1t = (_Float16*)(ws + alloc((size_t)EE*HH*DD*2));
  _Float16* w2t = (_Float16*)(ws + alloc((size_t)EE*DD*HH*2));
  // o2: [2][NPAIRS][DD] f32 = 2*8192*1024*4 B == E*H*D*2 B == w1t size exactly.
  // w1t is dead after gemm1; alias.
  float* o2 = (float*)w1t;

  k_init<<<1, 64, 0, stream>>>(counts);
  k_gate<<<MTOK/4, 256, 0, stream>>>(x, gw, gb, counts, topi, topg);
  k_prefix<<<1, 64, 0, stream>>>(counts, offs, cursor);
  k_build<<<MTOK/256, 256, 0, stream>>>(topi, topg, cursor, tok_of, gate_of, slot_of);
  k_gather<<<NPAIRS, 256, 0, stream>>>(x, tok_of, xg);
  k_transpose<<<dim3(HH/64, DD/64, EE), 256, 0, stream>>>(w1, w1t, DD, HH);
  k_transpose<<<dim3(DD/64, HH/64, EE), 256, 0, stream>>>(w2, w2t, HH, DD);
  k_gemm<0,1,DD,HH><<<(HH/128)*(MTOK/128)*EE, 256, 0, stream>>>(
      xg, w1t, b1, offs, counts, gate_of, hb, nullptr);
  k_gemm<1,2,HH,DD><<<(DD/128)*(MTOK/128)*EE*2, 256, 0, stream>>>(
      hb, w2t, b2, offs, counts, gate_of, nullptr, o2);
  k_combine<<<MTOK, 256, 0, stream>>>(o2, slot_of, out);
}